// Round 1
// baseline (211.164 us; speedup 1.0000x reference)
//
#include <hip/hip_runtime.h>
#include <hip/hip_bf16.h>

// Problem constants
#define NROW 8192
#define DDIM 512
#define TEMP_INV 20.0f      // 1/0.05
#define SHIFT 20.0f         // sim <= 20, accumulate exp(sim-20)

#define BM 128
#define BK 64
#define KT (DDIM / BK)      // 8 K-tiles

typedef __attribute__((ext_vector_type(8))) short short8;
typedef __attribute__((ext_vector_type(4))) float f32x4;

// Direct global->LDS async copy, 16B per lane. LDS dest must be the
// wave-uniform base; HW writes lane l at base + l*16.
__device__ __forceinline__ void gload16(const __hip_bfloat16* g, __hip_bfloat16* l) {
  __builtin_amdgcn_global_load_lds(
      (const __attribute__((address_space(1))) void*)g,
      (__attribute__((address_space(3))) void*)l,
      16, 0, 0);
}

// -------------------------------------------------------------------------
// Kernel 1: row-normalize both inputs to bf16 (z1 additionally scaled by
// 1/temperature), zero the rowsum accumulator. One wave per row.
// -------------------------------------------------------------------------
__global__ __launch_bounds__(256) void normalize_rows(
    const float* __restrict__ z1, const float* __restrict__ z2,
    __hip_bfloat16* __restrict__ z1n, __hip_bfloat16* __restrict__ z2n,
    float* __restrict__ rowsum) {
  int row = blockIdx.x * 4 + (threadIdx.x >> 6);   // 0..16383
  int lane = threadIdx.x & 63;

  const float* src;
  __hip_bfloat16* dst;
  float numer;
  if (row < NROW) {
    src = z1 + (size_t)row * DDIM;
    dst = z1n + (size_t)row * DDIM;
    numer = TEMP_INV;
    if (lane == 0) rowsum[row] = 0.0f;
  } else {
    int r = row - NROW;
    src = z2 + (size_t)r * DDIM;
    dst = z2n + (size_t)r * DDIM;
    numer = 1.0f;
  }

  float4 v0 = *reinterpret_cast<const float4*>(src + lane * 8);
  float4 v1 = *reinterpret_cast<const float4*>(src + lane * 8 + 4);
  float ss = v0.x * v0.x + v0.y * v0.y + v0.z * v0.z + v0.w * v0.w +
             v1.x * v1.x + v1.y * v1.y + v1.z * v1.z + v1.w * v1.w;
#pragma unroll
  for (int off = 32; off; off >>= 1) ss += __shfl_xor(ss, off);

  float scale = numer / fmaxf(sqrtf(ss), 1e-8f);

  float vals[8] = {v0.x, v0.y, v0.z, v0.w, v1.x, v1.y, v1.z, v1.w};
  union { __hip_bfloat16 h[8]; uint4 q; } pk;
#pragma unroll
  for (int j = 0; j < 8; ++j) pk.h[j] = __float2bfloat16(vals[j] * scale);
  *reinterpret_cast<uint4*>(dst + lane * 8) = pk.q;
}

// -------------------------------------------------------------------------
// Kernel 2: fused GEMM (dots = z1n @ z2n^T, both row-major N x D) + exp
// epilogue + per-row sum-of-exp atomic accumulation.
// 128x128 tile, BK=64, 4 waves (2x2 of 64x64), 16x16x32 bf16 MFMA.
// LDS staged via global_load_lds with XOR-swizzled SOURCE addresses
// (linear LDS dest) + matching XOR on the ds_read side (m201 pattern).
// -------------------------------------------------------------------------
__global__ __launch_bounds__(256) void gemm_lse(
    const __hip_bfloat16* __restrict__ An,   // z1n [N][D]
    const __hip_bfloat16* __restrict__ Bn,   // z2n [N][D]
    float* __restrict__ rowsum) {
  __shared__ __align__(16) __hip_bfloat16 Asl[BM * BK];
  __shared__ __align__(16) __hip_bfloat16 Bsl[BM * BK];

  int bid = blockIdx.x;
  int bx = bid & 63;          // col-block
  int by = bid >> 6;          // row-block
  int brow = by * BM;
  int bcol = bx * BM;

  int tid = threadIdx.x;
  int w = tid >> 6;           // wave 0..3
  int lane = tid & 63;
  int wr = w >> 1;            // wave-row 0..1
  int wc = w & 1;             // wave-col 0..1

  f32x4 acc[4][4];
#pragma unroll
  for (int m = 0; m < 4; ++m)
#pragma unroll
    for (int n = 0; n < 4; ++n) acc[m][n] = (f32x4)0.0f;

  // ---- staging address setup (per-lane) ----
  // Lane l lands in LDS at wave_base + l*16 -> local row l>>3, 16B-slot l&7.
  // We want LDS[row][u] to hold global slot u ^ (row&7)  (XOR swizzle).
  int drow = lane >> 3;                 // 0..7 local dest row
  int sslot = (lane & 7) ^ drow;        // swizzled source slot
  const __hip_bfloat16* ag =
      An + (size_t)(brow + w * 32 + drow) * DDIM + sslot * 8;
  const __hip_bfloat16* bg =
      Bn + (size_t)(bcol + w * 32 + drow) * DDIM + sslot * 8;

  // ---- fragment read setup ----
  int rA = wr * 64 + (lane & 15);       // + m*16 : A row within tile
  int rB = wc * 64 + (lane & 15);       // + n*16 : B row within tile
  int hi = lane >> 4;                   // 0..3 k-group
  int x7 = lane & 7;                    // == row&7 for all fragments

  for (int kt = 0; kt < KT; ++kt) {
    // stage A & B tiles: 4 x 8-row chunks per wave each
#pragma unroll
    for (int t = 0; t < 4; ++t) {
      gload16(ag + (size_t)(t * 8) * DDIM + kt * 64,
              &Asl[(w * 32 + t * 8) * BK]);
      gload16(bg + (size_t)(t * 8) * DDIM + kt * 64,
              &Bsl[(w * 32 + t * 8) * BK]);
    }
    __syncthreads();

#pragma unroll
    for (int kk = 0; kk < 2; ++kk) {
      short8 af[4], bf[4];
      int u = (((kk * 4) + hi) ^ x7) * 8;   // swizzled 16B-slot -> elem offset
#pragma unroll
      for (int m = 0; m < 4; ++m)
        af[m] = *reinterpret_cast<const short8*>(&Asl[(rA + m * 16) * BK + u]);
#pragma unroll
      for (int n = 0; n < 4; ++n)
        bf[n] = *reinterpret_cast<const short8*>(&Bsl[(rB + n * 16) * BK + u]);
#pragma unroll
      for (int m = 0; m < 4; ++m)
#pragma unroll
        for (int n = 0; n < 4; ++n)
          acc[m][n] = __builtin_amdgcn_mfma_f32_16x16x32_bf16(
              af[m], bf[n], acc[m][n], 0, 0, 0);
    }
    __syncthreads();
  }

  // ---- epilogue: exp(sim - 20), row-partial sums, atomic accumulate ----
  // C/D layout: col = lane&15, row = (lane>>4)*4 + reg  [m89/m91]
  const float L2E = 1.4426950408889634f;
  const float NEG = -SHIFT * 1.4426950408889634f;  // -28.8539...
#pragma unroll
  for (int m = 0; m < 4; ++m) {
#pragma unroll
    for (int r = 0; r < 4; ++r) {
      float s = 0.0f;
#pragma unroll
      for (int n = 0; n < 4; ++n)
        s += exp2f(fmaf(acc[m][n][r], L2E, NEG));
      // reduce across the 16 lanes sharing (lane>>4): they hold distinct cols
      s += __shfl_xor(s, 1);
      s += __shfl_xor(s, 2);
      s += __shfl_xor(s, 4);
      s += __shfl_xor(s, 8);
      if ((lane & 15) == 0)
        atomicAdd(&rowsum[brow + wr * 64 + m * 16 + hi * 4 + r], s);
    }
  }
}

// -------------------------------------------------------------------------
// Kernel 3: out = -( mean_i( log(rowsum_i) + 20 ) )
// -------------------------------------------------------------------------
__global__ __launch_bounds__(256) void finalize_lse(
    const float* __restrict__ rowsum, float* __restrict__ out) {
  __shared__ float sm[4];
  float s = 0.0f;
  for (int i = threadIdx.x; i < NROW; i += 256) s += logf(rowsum[i]);
#pragma unroll
  for (int off = 32; off; off >>= 1) s += __shfl_xor(s, off);
  int w = threadIdx.x >> 6;
  if ((threadIdx.x & 63) == 0) sm[w] = s;
  __syncthreads();
  if (threadIdx.x == 0) {
    float t = sm[0] + sm[1] + sm[2] + sm[3];
    out[0] = -(t / (float)NROW + SHIFT);
  }
}

// -------------------------------------------------------------------------
extern "C" void kernel_launch(void* const* d_in, const int* in_sizes, int n_in,
                              void* d_out, int out_size, void* d_ws,
                              size_t ws_size, hipStream_t stream) {
  const float* z1 = (const float*)d_in[0];
  const float* z2 = (const float*)d_in[1];
  float* out = (float*)d_out;

  char* ws = (char*)d_ws;
  __hip_bfloat16* z1n = (__hip_bfloat16*)ws;                               // 8 MB
  __hip_bfloat16* z2n = (__hip_bfloat16*)(ws + (size_t)NROW * DDIM * 2);   // 8 MB
  float* rowsum = (float*)(ws + (size_t)2 * NROW * DDIM * 2);              // 32 KB

  normalize_rows<<<dim3((2 * NROW) / 4), dim3(256), 0, stream>>>(z1, z2, z1n,
                                                                 z2n, rowsum);
  gemm_lse<<<dim3((NROW / BM) * (NROW / BM)), dim3(256), 0, stream>>>(
      z1n, z2n, rowsum);
  finalize_lse<<<dim3(1), dim3(256), 0, stream>>>(rowsum, out);
}

// Round 2
// 207.708 us; speedup vs baseline: 1.0166x; 1.0166x over previous
//
#include <hip/hip_runtime.h>
#include <hip/hip_bf16.h>

// Problem constants
#define NROW 8192
#define DDIM 512
#define TEMP_INV 20.0f      // 1/0.05
#define SHIFT 20.0f         // sim <= 20, accumulate exp(sim-20)

// GEMM geometry: 256x256 tile, BK=32, 8 waves (2 M x 4 N), 4-deep LDS ring
#define BM 256
#define BN 256
#define BK 32
#define KT (DDIM / BK)          // 16 K-steps
#define TILE_ELE (BM * BK)      // 8192 bf16 per matrix tile
#define BUF_ELE (2 * TILE_ELE)  // A + B per ring slot
#define LDS_BYTES (4 * BUF_ELE * 2)  // 131072

typedef __attribute__((ext_vector_type(8))) short short8;
typedef __attribute__((ext_vector_type(4))) float f32x4;

__device__ __forceinline__ void gload16(const __hip_bfloat16* g, __hip_bfloat16* l) {
  __builtin_amdgcn_global_load_lds(
      (const __attribute__((address_space(1))) void*)g,
      (__attribute__((address_space(3))) void*)l,
      16, 0, 0);
}

// -------------------------------------------------------------------------
// Kernel 1: row-normalize both inputs to bf16 (z1 additionally scaled by
// 1/temperature), zero the rowsum accumulator. One wave per row.
// -------------------------------------------------------------------------
__global__ __launch_bounds__(256) void normalize_rows(
    const float* __restrict__ z1, const float* __restrict__ z2,
    __hip_bfloat16* __restrict__ z1n, __hip_bfloat16* __restrict__ z2n,
    float* __restrict__ rowsum) {
  int row = blockIdx.x * 4 + (threadIdx.x >> 6);   // 0..16383
  int lane = threadIdx.x & 63;

  const float* src;
  __hip_bfloat16* dst;
  float numer;
  if (row < NROW) {
    src = z1 + (size_t)row * DDIM;
    dst = z1n + (size_t)row * DDIM;
    numer = TEMP_INV;
    if (lane == 0) rowsum[row] = 0.0f;
  } else {
    int r = row - NROW;
    src = z2 + (size_t)r * DDIM;
    dst = z2n + (size_t)r * DDIM;
    numer = 1.0f;
  }

  float4 v0 = *reinterpret_cast<const float4*>(src + lane * 8);
  float4 v1 = *reinterpret_cast<const float4*>(src + lane * 8 + 4);
  float ss = v0.x * v0.x + v0.y * v0.y + v0.z * v0.z + v0.w * v0.w +
             v1.x * v1.x + v1.y * v1.y + v1.z * v1.z + v1.w * v1.w;
#pragma unroll
  for (int off = 32; off; off >>= 1) ss += __shfl_xor(ss, off);

  float scale = numer / fmaxf(sqrtf(ss), 1e-8f);

  float vals[8] = {v0.x, v0.y, v0.z, v0.w, v1.x, v1.y, v1.z, v1.w};
  union { __hip_bfloat16 h[8]; uint4 q; } pk;
#pragma unroll
  for (int j = 0; j < 8; ++j) pk.h[j] = __float2bfloat16(vals[j] * scale);
  *reinterpret_cast<uint4*>(dst + lane * 8) = pk.q;
}

// -------------------------------------------------------------------------
// Kernel 2: fused GEMM (dots = z1n @ z2n^T) + exp epilogue + per-row
// sum-of-exp atomic accumulation.
// 256x256 tile, BK=32, 8 waves (wave = 128x64 of C), 16x16x32 bf16 MFMA.
// 4-deep LDS ring: STAGE(kt+3) each step, counted vmcnt(8) (never 0 in the
// main loop), ONE barrier per K-step. Source-side XOR swizzle
// (slot ^ (row&3)) with linear global_load_lds dest, same XOR on ds_read.
// -------------------------------------------------------------------------
__global__ __launch_bounds__(512, 2) void gemm_lse(
    const __hip_bfloat16* __restrict__ An,   // z1n [N][D]
    const __hip_bfloat16* __restrict__ Bn,   // z2n [N][D]
    float* __restrict__ rowsum) {
  extern __shared__ __align__(16) __hip_bfloat16 lds[];

  const int bid = blockIdx.x;
  const int bx = bid & 31;            // 32 col-blocks
  const int by = bid >> 5;            // 32 row-blocks
  const int brow = by * BM;
  const int bcol = bx * BN;

  const int tid = threadIdx.x;
  const int w = tid >> 6;             // wave 0..7
  const int lane = tid & 63;
  const int wr = w >> 2;              // wave-row 0..1 (128 rows each)
  const int wc = w & 3;               // wave-col 0..3 (64 cols each)

  f32x4 acc[8][4];
#pragma unroll
  for (int m = 0; m < 8; ++m)
#pragma unroll
    for (int n = 0; n < 4; ++n) acc[m][n] = (f32x4)0.0f;

  // ---- staging source addresses (per-lane, pre-swizzled) ----
  // gload16 writes lane l at wave-base + 16*l -> row (l>>2), 16B-slot (l&3).
  // LDS[row][slot'] must hold global slot slot' ^ (row&3).
  const int srow = w * 32 + (lane >> 2);            // staging row in tile
  const int sslot = (lane & 3) ^ ((lane >> 2) & 3); // swizzled source slot
  const __hip_bfloat16* agA = An + (size_t)(brow + srow) * DDIM + sslot * 8;
  const __hip_bfloat16* agB = Bn + (size_t)(bcol + srow) * DDIM + sslot * 8;
  const int da0 = (w * 32) * BK;       // wave-uniform LDS dest offsets
  const int da1 = (w * 32 + 16) * BK;

  // ---- fragment read offsets ----
  const int hi = lane >> 4;                       // k-group 0..3
  const int u8 = (hi ^ (lane & 3)) * 8;           // swizzled slot -> elem off
  const int rA = wr * 128 + (lane & 15);          // + m*16
  const int rB = wc * 64 + (lane & 15);           // + n*16

  auto STAGE = [&](int d, int kt) {
    __hip_bfloat16* base = lds + (size_t)d * BUF_ELE;
    const __hip_bfloat16* ga = agA + kt * BK;
    const __hip_bfloat16* gb = agB + kt * BK;
    gload16(ga, base + da0);
    gload16(ga + (size_t)16 * DDIM, base + da1);
    gload16(gb, base + TILE_ELE + da0);
    gload16(gb + (size_t)16 * DDIM, base + TILE_ELE + da1);
  };

  auto COMPUTE = [&](int d) {
    const __hip_bfloat16* Ab = lds + (size_t)d * BUF_ELE;
    const __hip_bfloat16* Bb = Ab + TILE_ELE;
    short8 af[8], bfr[4];
#pragma unroll
    for (int n = 0; n < 4; ++n)
      bfr[n] = *reinterpret_cast<const short8*>(&Bb[(rB + n * 16) * BK + u8]);
#pragma unroll
    for (int m = 0; m < 8; ++m)
      af[m] = *reinterpret_cast<const short8*>(&Ab[(rA + m * 16) * BK + u8]);
#pragma unroll
    for (int m = 0; m < 8; ++m)
#pragma unroll
      for (int n = 0; n < 4; ++n)
        acc[m][n] = __builtin_amdgcn_mfma_f32_16x16x32_bf16(
            af[m], bfr[n], acc[m][n], 0, 0, 0);
  };

  // ---- prologue: fill 3 ring slots ----
  STAGE(0, 0);
  STAGE(1, 1);
  STAGE(2, 2);
  asm volatile("s_waitcnt vmcnt(8)" ::: "memory");   // tile 0 landed
  __builtin_amdgcn_s_barrier();
  __builtin_amdgcn_sched_barrier(0);

  // ---- main loop: stage kt+3, compute kt, wait tile kt+1 (vmcnt counted) --
  for (int kt = 0; kt < KT - 3; ++kt) {              // kt = 0..12
    STAGE((kt + 3) & 3, kt + 3);
    COMPUTE(kt & 3);
    asm volatile("s_waitcnt vmcnt(8)" ::: "memory"); // tile kt+1 landed
    __builtin_amdgcn_s_barrier();
    __builtin_amdgcn_sched_barrier(0);
  }
  // ---- epilogue peel: kt = 13, 14, 15 (drain 4 -> 0) ----
  COMPUTE(13 & 3);
  asm volatile("s_waitcnt vmcnt(4)" ::: "memory");   // tile 14 landed
  __builtin_amdgcn_s_barrier();
  __builtin_amdgcn_sched_barrier(0);
  COMPUTE(14 & 3);
  asm volatile("s_waitcnt vmcnt(0)" ::: "memory");   // tile 15 landed
  __builtin_amdgcn_s_barrier();
  __builtin_amdgcn_sched_barrier(0);
  COMPUTE(15 & 3);

  // ---- epilogue: exp(sim - 20), 16-lane col reduce, atomic accumulate ----
  // C/D layout: col = lane&15, row = (lane>>4)*4 + reg  [m89/m91]
  const float L2E = 1.4426950408889634f;
  const float NEG = -SHIFT * 1.4426950408889634f;
#pragma unroll
  for (int m = 0; m < 8; ++m) {
#pragma unroll
    for (int r = 0; r < 4; ++r) {
      float s = 0.0f;
#pragma unroll
      for (int n = 0; n < 4; ++n)
        s += exp2f(fmaf(acc[m][n][r], L2E, NEG));
      s += __shfl_xor(s, 1);
      s += __shfl_xor(s, 2);
      s += __shfl_xor(s, 4);
      s += __shfl_xor(s, 8);
      if ((lane & 15) == 0)
        atomicAdd(&rowsum[brow + wr * 128 + m * 16 + hi * 4 + r], s);
    }
  }
}

// -------------------------------------------------------------------------
// Kernel 3: out = -( mean_i( log(rowsum_i) + 20 ) )
// -------------------------------------------------------------------------
__global__ __launch_bounds__(1024) void finalize_lse(
    const float* __restrict__ rowsum, float* __restrict__ out) {
  __shared__ float sm[16];
  float s = 0.0f;
  for (int i = threadIdx.x; i < NROW; i += 1024) s += logf(rowsum[i]);
#pragma unroll
  for (int off = 32; off; off >>= 1) s += __shfl_xor(s, off);
  int w = threadIdx.x >> 6;
  if ((threadIdx.x & 63) == 0) sm[w] = s;
  __syncthreads();
  if (threadIdx.x == 0) {
    float t = 0.0f;
#pragma unroll
    for (int i = 0; i < 16; ++i) t += sm[i];
    out[0] = -(t / (float)NROW + SHIFT);
  }
}

// -------------------------------------------------------------------------
extern "C" void kernel_launch(void* const* d_in, const int* in_sizes, int n_in,
                              void* d_out, int out_size, void* d_ws,
                              size_t ws_size, hipStream_t stream) {
  const float* z1 = (const float*)d_in[0];
  const float* z2 = (const float*)d_in[1];
  float* out = (float*)d_out;

  char* ws = (char*)d_ws;
  __hip_bfloat16* z1n = (__hip_bfloat16*)ws;                               // 8 MB
  __hip_bfloat16* z2n = (__hip_bfloat16*)(ws + (size_t)NROW * DDIM * 2);   // 8 MB
  float* rowsum = (float*)(ws + (size_t)2 * NROW * DDIM * 2);              // 32 KB

  // Allow 128 KiB dynamic LDS (idempotent; not a stream op, capture-safe).
  static bool attr_set = false;
  if (!attr_set) {
    hipFuncSetAttribute((const void*)gemm_lse,
                        hipFuncAttributeMaxDynamicSharedMemorySize, LDS_BYTES);
    attr_set = true;
  }

  normalize_rows<<<dim3((2 * NROW) / 4), dim3(256), 0, stream>>>(z1, z2, z1n,
                                                                 z2n, rowsum);
  gemm_lse<<<dim3((NROW / BM) * (NROW / BN)), dim3(512), LDS_BYTES, stream>>>(
      z1n, z2n, rowsum);
  finalize_lse<<<dim3(1), dim3(1024), 0, stream>>>(rowsum, out);
}